// Round 3
// baseline (197.923 us; speedup 1.0000x reference)
//
#include <hip/hip_runtime.h>
#include <math.h>

typedef __bf16 bf16_t;
typedef __bf16 bf16x4 __attribute__((ext_vector_type(4)));
typedef __bf16 bf16x8 __attribute__((ext_vector_type(8)));
typedef float  f32x4  __attribute__((ext_vector_type(4)));
typedef float  f32x8  __attribute__((ext_vector_type(8)));

#define NHEADS 16
#define DH 64
#define SEQ 2048
#define DMODEL 1024

static __device__ __forceinline__ f32x4 mfma_bf16(bf16x8 a, bf16x8 b, f32x4 c) {
  return __builtin_amdgcn_mfma_f32_16x16x32_bf16(a, b, c, 0, 0, 0);
}

// async global->LDS, 16B per lane; LDS dest = wave-uniform base + lane*16
static __device__ __forceinline__ void load_lds16(const bf16_t* g, bf16_t* l) {
  __builtin_amdgcn_global_load_lds(
      (const __attribute__((address_space(1))) void*)g,
      (__attribute__((address_space(3))) void*)l, 16, 0, 0);
}

// ---------------- f32 -> bf16 pre-convert ----------------
// flat dst layout: x(4M) | Wq(1M) | Wk(1M) | Wv(1M) | Wo(1M) elems
__global__ __launch_bounds__(256) void convert_kernel(
    const float* __restrict__ x, const float* __restrict__ Wq,
    const float* __restrict__ Wk, const float* __restrict__ Wv,
    const float* __restrict__ Wo, bf16_t* __restrict__ dst)
{
  const size_t idx = ((size_t)blockIdx.x * 256 + threadIdx.x) * 8;
  const size_t XN = (size_t)4096 * DMODEL;
  const float* src;
  size_t off;
  if (idx < XN) { src = x; off = idx; }
  else {
    size_t r = idx - XN;
    int q = (int)(r >> 20);
    off = r & ((size_t)(1u << 20) - 1);
    src = (q == 0) ? Wq : (q == 1) ? Wk : (q == 2) ? Wv : Wo;
  }
  f32x8 v = *(const f32x8*)(src + off);
  bf16x8 o;
  #pragma unroll
  for (int j = 0; j < 8; ++j) o[j] = (bf16_t)v[j];
  *(bf16x8*)(dst + idx) = o;
}

// ---------------- shared 128x128 GEMM core (m97 structure + LDS swizzle) ----
static __device__ __forceinline__ void gemm128(
    const bf16_t* __restrict__ A, const bf16_t* __restrict__ B,
    bf16_t* As, bf16_t* Bs, f32x4 (&acc)[4][4])
{
  const int t    = threadIdx.x;
  const int w    = t >> 6;
  const int lane = t & 63;
  const int col  = lane & 15;
  const int quad = lane >> 4;
  const int wm   = w >> 1;
  const int wn   = w & 1;

  const int sr = t >> 2;
  const int sc = (t & 3) ^ (sr & 3);          // swizzled source chunk
  const bf16_t* ga = A + (size_t)sr * DMODEL + sc * 8;
  const bf16_t* gb = B + (size_t)sr * DMODEL + sc * 8;
  bf16_t* la = As + w * 512;
  bf16_t* lb = Bs + w * 512;

  const int swz = (quad ^ (col & 3)) * 8;     // read-side XOR

  for (int kk = 0; kk < DMODEL; kk += 32) {
    load_lds16(ga + kk, la);
    load_lds16(ga + (size_t)64 * DMODEL + kk, la + 2048);
    load_lds16(gb + kk, lb);
    load_lds16(gb + (size_t)64 * DMODEL + kk, lb + 2048);
    __syncthreads();

    bf16x8 af[4], bfr[4];
    #pragma unroll
    for (int i = 0; i < 4; ++i) {
      af[i]  = *(const bf16x8*)(As + (wm * 64 + i * 16 + col) * 32 + swz);
      bfr[i] = *(const bf16x8*)(Bs + (wn * 64 + i * 16 + col) * 32 + swz);
    }
    #pragma unroll
    for (int mt = 0; mt < 4; ++mt)
      #pragma unroll
      for (int nt = 0; nt < 4; ++nt)
        acc[mt][nt] = mfma_bf16(af[mt], bfr[nt], acc[mt][nt]);
    __syncthreads();
  }
}

// ---------------- QKV projection ----------------
__global__ __launch_bounds__(256) void qkv_gemm_kernel(
    const bf16_t* __restrict__ xb, const bf16_t* __restrict__ Wall,
    bf16_t* __restrict__ Qb, bf16_t* __restrict__ Kb, bf16_t* __restrict__ Vt)
{
  __shared__ __align__(16) bf16_t As[128 * 32];
  __shared__ __align__(16) bf16_t Bs[128 * 32];
  f32x4 acc[4][4] = {};
  const int m0 = blockIdx.x * 128;
  const int n0 = blockIdx.y * 128;
  gemm128(xb + (size_t)m0 * DMODEL, Wall + (size_t)n0 * DMODEL, As, Bs, acc);

  const int t = threadIdx.x;
  const int lane = t & 63, w = t >> 6;
  const int col = lane & 15, quad = lane >> 4;
  const int wm = w >> 1, wn = w & 1;
  const int nw0 = n0 + wn * 64;
  const int wt  = nw0 >> 10;          // 0=Q, 1=K, 2=V
  const int h   = (nw0 >> 6) & 15;
  const int mbase = m0 + wm * 64;

  if (wt < 2) {
    bf16_t* Out = (wt == 0) ? Qb : Kb;
    #pragma unroll
    for (int mt = 0; mt < 4; ++mt) {
      #pragma unroll
      for (int nt = 0; nt < 4; ++nt) {
        const int d = nt * 16 + col;
        #pragma unroll
        for (int r = 0; r < 4; ++r) {
          const int m = mbase + mt * 16 + quad * 4 + r;
          const int b = m >> 11, s = m & (SEQ - 1);
          Out[((size_t)(b * NHEADS + h) * SEQ + s) * DH + d] = (bf16_t)acc[mt][nt][r];
        }
      }
    }
  } else {
    #pragma unroll
    for (int mt = 0; mt < 4; ++mt) {
      const int m = mbase + mt * 16 + quad * 4;
      const int b = m >> 11, s = m & (SEQ - 1);
      #pragma unroll
      for (int nt = 0; nt < 4; ++nt) {
        const int d = nt * 16 + col;
        bf16x4 v4 = { (bf16_t)acc[mt][nt][0], (bf16_t)acc[mt][nt][1],
                      (bf16_t)acc[mt][nt][2], (bf16_t)acc[mt][nt][3] };
        *(bf16x4*)(Vt + ((size_t)(b * NHEADS + h) * DH + d) * SEQ + s) = v4;
      }
    }
  }
}

// ---------------- RoPE (in-place on Q and K) ----------------
__global__ __launch_bounds__(256) void rope_kernel(
    bf16_t* __restrict__ Qb, bf16_t* __restrict__ Kb, const int* __restrict__ tpos)
{
  const int idx = blockIdx.x * 256 + threadIdx.x;
  const int i  = idx & 31;
  const int s  = (idx >> 5) & (SEQ - 1);
  const int bh = idx >> 16;

  const float pos  = (float)tpos[s];
  const float freq = expf((float)i * -0.28782313662425573f);
  const float ang  = pos * freq;
  const float cs = cosf(ang), sn = sinf(ang);

  const size_t base = ((size_t)bh * SEQ + s) * DH + 2 * i;
  {
    float e = (float)Qb[base], o = (float)Qb[base + 1];
    Qb[base]     = (bf16_t)(e * cs - o * sn);
    Qb[base + 1] = (bf16_t)(e * sn + o * cs);
  }
  {
    float e = (float)Kb[base], o = (float)Kb[base + 1];
    Kb[base]     = (bf16_t)(e * cs - o * sn);
    Kb[base + 1] = (bf16_t)(e * sn + o * cs);
  }
}

// ---------------- Flash attention v9 ----------------
// v8 -> v9: oversubscribed backfill scheduling. Unpaired 64-row q-tiles,
// 128-thread (2-wave) blocks at R=32 rows/wave. Grid (32 bh, 32 qt) = 1024
// blocks, LONGEST FIRST (qt = 31 - y): durations qt+1 in 1..32 iters, 43KB
// LDS -> 3 blocks/CU resident (6 waves/CU), ~4 blocks/CU total so the HW
// scheduler backfills short blocks behind long ones. Fixes v7/v8's collapse:
// equal-block pairing forces waves/CU = 128/R (R=32 -> 1 wave/SIMD, solo-rate
// ~3800cyc/iter); backfill keeps 3 independent blocks in flight instead.
// Diagonal tile: wave 0 (local rows 0-31) skips keys 32-63 entirely (fully
// masked -> no QK, no P write, no plane-b PV); wave 1 predicates them.
__global__ __launch_bounds__(128) void attn_kernel(
    const bf16_t* __restrict__ Qb, const bf16_t* __restrict__ Kb,
    const bf16_t* __restrict__ Vt, bf16_t* __restrict__ attn)
{
  __shared__ __align__(16) bf16_t Ks[2][4096];   // [buf][plane(2) x 64 keys x 32 d]
  __shared__ __align__(16) bf16_t Vs[2][4096];   // [buf][plane(2) x 64 d x 32 keys]
  __shared__ __align__(16) bf16_t Ps[2][2560];   // per wave: 2 qgrp x 2 planes x 640

  const int t    = threadIdx.x;
  const int wave = t >> 6;                       // 0..1
  const int lane = t & 63;
  const int col  = lane & 15;
  const int quad = lane >> 4;
  const int bh = blockIdx.x;
  const int h  = bh & 15;
  const int b  = bh >> 4;
  const int qt = 31 - blockIdx.y;                // longest blocks dispatch first

  const size_t hoff = (size_t)(b * NHEADS + h) * SEQ * DH;
  const bf16_t* Qh = Qb + hoff;
  const bf16_t* Kh = Kb + hoff;
  const bf16_t* Vh = Vt + hoff;                  // (d,s), row stride SEQ

  // Q B-fragments: 2 q-groups x 2 d-chunks, pre-scaled by 1/8 * log2(e)
  const int qr = qt * 64 + wave * 32 + col;
  bf16x8 q00 = *(const bf16x8*)(Qh + (size_t)qr * DH + quad * 8);
  bf16x8 q01 = *(const bf16x8*)(Qh + (size_t)qr * DH + 32 + quad * 8);
  bf16x8 q10 = *(const bf16x8*)(Qh + (size_t)(qr + 16) * DH + quad * 8);
  bf16x8 q11 = *(const bf16x8*)(Qh + (size_t)(qr + 16) * DH + 32 + quad * 8);
  #pragma unroll
  for (int j = 0; j < 8; ++j) {
    const float sc = 0.1803368801111191f;
    q00[j] = (bf16_t)((float)q00[j] * sc); q01[j] = (bf16_t)((float)q01[j] * sc);
    q10[j] = (bf16_t)((float)q10[j] * sc); q11[j] = (bf16_t)((float)q11[j] * sc);
  }

  // staging map: thread t -> plane-row t>>2 (0..31), swizzled 16B chunk
  const int sr  = t >> 2;
  const int scs = (t & 3) ^ (sr & 3);            // swizzled source chunk
  const int lbase = t * 8;                       // elems (covers 32 rows/call)
  const bf16_t* kg0 = Kh + (size_t)sr * DH + scs * 8;
  const bf16_t* vg0 = Vh + (size_t)sr * SEQ + scs * 8;

  // prologue: stage k-tile 0 into buf 0 (8 calls: 2 row-halves x 2 planes x K,V)
  load_lds16(kg0,                &Ks[0][lbase]);
  load_lds16(kg0 + 32 * DH,      &Ks[0][1024 + lbase]);
  load_lds16(kg0 + 32,           &Ks[0][2048 + lbase]);
  load_lds16(kg0 + 32 * DH + 32, &Ks[0][3072 + lbase]);
  load_lds16(vg0,                 &Vs[0][lbase]);
  load_lds16(vg0 + 32 * SEQ,      &Vs[0][1024 + lbase]);
  load_lds16(vg0 + 32,            &Vs[0][2048 + lbase]);
  load_lds16(vg0 + 32 * SEQ + 32, &Vs[0][3072 + lbase]);

  f32x4 o[4][2] = {};
  float lsum0 = 0.0f, lsum1 = 0.0f;
  bf16_t* P = Ps[wave];
  const int pwoff = col * 40 + quad * 4;
  const int kswz  = (quad ^ (col & 3)) * 8;      // K/V read-side XOR
  const int lim0  = wave * 32 + col;             // causal limit, q-group 0
  const int lim1  = lim0 + 16;                   // q-group 1

  for (int it = 0; it <= qt; ++it) {
    const int buf = it & 1;
    __syncthreads();   // DMA for tile it complete; buf^1 free

    if (it < qt) {     // prefetch next k-tile
      const bf16_t* kg = kg0 + (size_t)(it + 1) * 64 * DH;
      const bf16_t* vg = vg0 + (it + 1) * 64;
      bf16_t* Kd = Ks[buf ^ 1];
      bf16_t* Vd = Vs[buf ^ 1];
      load_lds16(kg,                Kd + lbase);
      load_lds16(kg + 32 * DH,      Kd + 1024 + lbase);
      load_lds16(kg + 32,           Kd + 2048 + lbase);
      load_lds16(kg + 32 * DH + 32, Kd + 3072 + lbase);
      load_lds16(vg,                Vd + lbase);
      load_lds16(vg + 32 * SEQ,     Vd + 1024 + lbase);
      load_lds16(vg + 32,           Vd + 2048 + lbase);
      load_lds16(vg + 32 * SEQ + 32, Vd + 3072 + lbase);
    }

    const bool diag = (it == qt);
    const bool full = (!diag) || (wave == 1);    // keys 32..63 relevant?
    const bf16_t* Kbuf = Ks[buf];
    const bf16_t* Vbuf = Vs[buf];

    // QK^T (rows=keys, cols=q) + softmax -> P. kt = 16-key group.
    #pragma unroll
    for (int kt = 0; kt < 2; ++kt) {
      const int R = 16 * kt + col;
      bf16x8 ka = *(const bf16x8*)(Kbuf + R * 32 + kswz);
      bf16x8 kb = *(const bf16x8*)(Kbuf + 2048 + R * 32 + kswz);
      f32x4 s0 = {}, s1 = {};
      s0 = mfma_bf16(ka, q00, s0);
      s0 = mfma_bf16(kb, q01, s0);
      s1 = mfma_bf16(ka, q10, s1);
      s1 = mfma_bf16(kb, q11, s1);
      const int kl = kt * 16 + quad * 4;
      bf16x4 p40, p41;
      #pragma unroll
      for (int r = 0; r < 4; ++r) {
        float p0 = (!diag || (kl + r <= lim0)) ? __builtin_amdgcn_exp2f(s0[r]) : 0.0f;
        float p1 = (!diag || (kl + r <= lim1)) ? __builtin_amdgcn_exp2f(s1[r]) : 0.0f;
        lsum0 += p0; lsum1 += p1;
        p40[r] = (bf16_t)p0; p41[r] = (bf16_t)p1;
      }
      *(bf16x4*)(P + (kt & 1) * 16 + pwoff) = p40;
      *(bf16x4*)(P + 1280 + (kt & 1) * 16 + pwoff) = p41;
    }
    if (full) {
      #pragma unroll
      for (int kt = 2; kt < 4; ++kt) {
        const int R = 16 * kt + col;
        bf16x8 ka = *(const bf16x8*)(Kbuf + R * 32 + kswz);
        bf16x8 kb = *(const bf16x8*)(Kbuf + 2048 + R * 32 + kswz);
        f32x4 s0 = {}, s1 = {};
        s0 = mfma_bf16(ka, q00, s0);
        s0 = mfma_bf16(kb, q01, s0);
        s1 = mfma_bf16(ka, q10, s1);
        s1 = mfma_bf16(kb, q11, s1);
        const int kl = kt * 16 + quad * 4;
        bf16x4 p40, p41;
        #pragma unroll
        for (int r = 0; r < 4; ++r) {
          float p0 = (!diag || (kl + r <= lim0)) ? __builtin_amdgcn_exp2f(s0[r]) : 0.0f;
          float p1 = (!diag || (kl + r <= lim1)) ? __builtin_amdgcn_exp2f(s1[r]) : 0.0f;
          lsum0 += p0; lsum1 += p1;
          p40[r] = (bf16_t)p0; p41[r] = (bf16_t)p1;
        }
        *(bf16x4*)(P + 640 + (kt & 1) * 16 + pwoff) = p40;
        *(bf16x4*)(P + 1920 + (kt & 1) * 16 + pwoff) = p41;
      }
    }

    // P B-fragments (balanced-bank b128 reads) + PV: o[d][q] += V' * P
    bf16x8 pf00 = *(const bf16x8*)(P + col * 40 + quad * 8);
    bf16x8 pf10 = *(const bf16x8*)(P + 1280 + col * 40 + quad * 8);
    #pragma unroll
    for (int dt = 0; dt < 4; ++dt) {
      bf16x8 va = *(const bf16x8*)(Vbuf + (16 * dt + col) * 32 + kswz);
      o[dt][0] = mfma_bf16(va, pf00, o[dt][0]);
      o[dt][1] = mfma_bf16(va, pf10, o[dt][1]);
    }
    if (full) {
      bf16x8 pf01 = *(const bf16x8*)(P + 640 + col * 40 + quad * 8);
      bf16x8 pf11 = *(const bf16x8*)(P + 1920 + col * 40 + quad * 8);
      #pragma unroll
      for (int dt = 0; dt < 4; ++dt) {
        bf16x8 vb = *(const bf16x8*)(Vbuf + 2048 + (16 * dt + col) * 32 + kswz);
        o[dt][0] = mfma_bf16(vb, pf01, o[dt][0]);
        o[dt][1] = mfma_bf16(vb, pf11, o[dt][1]);
      }
    }
  }

  // finalize: reduce lsum across quads, normalize, store
  float ls0 = lsum0, ls1 = lsum1;
  ls0 += __shfl_xor(ls0, 16, 64);
  ls0 += __shfl_xor(ls0, 32, 64);
  ls1 += __shfl_xor(ls1, 16, 64);
  ls1 += __shfl_xor(ls1, 32, 64);
  const float inv0 = 1.0f / ls0;
  const float inv1 = 1.0f / ls1;
  const size_t orow0 = (size_t)(b * SEQ + qr) * DMODEL + h * DH;
  const size_t orow1 = (size_t)(b * SEQ + qr + 16) * DMODEL + h * DH;
  #pragma unroll
  for (int dt = 0; dt < 4; ++dt) {
    bf16x4 v0 = { (bf16_t)(o[dt][0][0] * inv0), (bf16_t)(o[dt][0][1] * inv0),
                  (bf16_t)(o[dt][0][2] * inv0), (bf16_t)(o[dt][0][3] * inv0) };
    bf16x4 v1 = { (bf16_t)(o[dt][1][0] * inv1), (bf16_t)(o[dt][1][1] * inv1),
                  (bf16_t)(o[dt][1][2] * inv1), (bf16_t)(o[dt][1][3] * inv1) };
    *(bf16x4*)(attn + orow0 + dt * 16 + quad * 4) = v0;
    *(bf16x4*)(attn + orow1 + dt * 16 + quad * 4) = v1;
  }
}

// ---------------- Output projection (-> f32 d_out) ----------------
__global__ __launch_bounds__(256) void out_gemm_kernel(
    const bf16_t* __restrict__ Ab, const bf16_t* __restrict__ Wob,
    float* __restrict__ out)
{
  __shared__ __align__(16) bf16_t As[128 * 32];
  __shared__ __align__(16) bf16_t Bs[128 * 32];
  f32x4 acc[4][4] = {};
  const int m0 = blockIdx.x * 128;
  const int n0 = blockIdx.y * 128;
  gemm128(Ab + (size_t)m0 * DMODEL, Wob + (size_t)n0 * DMODEL, As, Bs, acc);

  const int t = threadIdx.x;
  const int lane = t & 63, w = t >> 6;
  const int col = lane & 15, quad = lane >> 4;
  const int wm = w >> 1, wn = w & 1;
  const int mbase = m0 + wm * 64;
  const int nbase = n0 + wn * 64;

  #pragma unroll
  for (int mt = 0; mt < 4; ++mt)
    #pragma unroll
    for (int nt = 0; nt < 4; ++nt)
      #pragma unroll
      for (int r = 0; r < 4; ++r)
        out[(size_t)(mbase + mt * 16 + quad * 4 + r) * DMODEL + nbase + nt * 16 + col] =
            acc[mt][nt][r];
}

extern "C" void kernel_launch(void* const* d_in, const int* in_sizes, int n_in,
                              void* d_out, int out_size, void* d_ws, size_t ws_size,
                              hipStream_t stream)
{
  (void)in_sizes; (void)n_in; (void)out_size; (void)ws_size;
  const float* x  = (const float*)d_in[0];
  const float* Wq = (const float*)d_in[1];
  const float* Wk = (const float*)d_in[2];
  const float* Wv = (const float*)d_in[3];
  const float* Wo = (const float*)d_in[4];
  const int* tpos = (const int*)d_in[5];
  float* out = (float*)d_out;

  const size_t M1 = (size_t)1024 * 1024;
  bf16_t* xb    = (bf16_t*)d_ws;                  // 4M elems
  bf16_t* Wall  = xb + 4 * M1;                    // Wq|Wk|Wv (3M)
  bf16_t* Wob   = xb + 7 * M1;                    // 1M
  bf16_t* Qb    = xb + 8 * M1;                    // 4M  (b,h,s,d)
  bf16_t* Kb    = Qb + 4 * M1;                    // 4M  (b,h,s,d)
  bf16_t* Vt    = Kb + 4 * M1;                    // 4M  (b,h,d,s)
  bf16_t* attnb = Vt + 4 * M1;                    // 4M  (b*s, h*d)

  convert_kernel<<<dim3(4096, 1, 1), dim3(256, 1, 1), 0, stream>>>(
      x, Wq, Wk, Wv, Wo, xb);
  qkv_gemm_kernel<<<dim3(32, 24, 1), dim3(256, 1, 1), 0, stream>>>(
      xb, Wall, Qb, Kb, Vt);
  rope_kernel<<<dim3(8192, 1, 1), dim3(256, 1, 1), 0, stream>>>(Qb, Kb, tpos);
  attn_kernel<<<dim3(32, 32, 1), dim3(128, 1, 1), 0, stream>>>(
      Qb, Kb, Vt, attnb);
  out_gemm_kernel<<<dim3(32, 8, 1), dim3(256, 1, 1), 0, stream>>>(
      attnb, Wob, out);
}

// Round 4
// 197.237 us; speedup vs baseline: 1.0035x; 1.0035x over previous
//
#include <hip/hip_runtime.h>
#include <math.h>

typedef __bf16 bf16_t;
typedef __bf16 bf16x4 __attribute__((ext_vector_type(4)));
typedef __bf16 bf16x8 __attribute__((ext_vector_type(8)));
typedef float  f32x4  __attribute__((ext_vector_type(4)));
typedef float  f32x8  __attribute__((ext_vector_type(8)));

#define NHEADS 16
#define DH 64
#define SEQ 2048
#define DMODEL 1024

static __device__ __forceinline__ f32x4 mfma_bf16(bf16x8 a, bf16x8 b, f32x4 c) {
  return __builtin_amdgcn_mfma_f32_16x16x32_bf16(a, b, c, 0, 0, 0);
}

// async global->LDS, 16B per lane; LDS dest = wave-uniform base + lane*16
static __device__ __forceinline__ void load_lds16(const bf16_t* g, bf16_t* l) {
  __builtin_amdgcn_global_load_lds(
      (const __attribute__((address_space(1))) void*)g,
      (__attribute__((address_space(3))) void*)l, 16, 0, 0);
}

// ---------------- f32 -> bf16 pre-convert ----------------
// flat dst layout: x(4M) | Wq(1M) | Wk(1M) | Wv(1M) | Wo(1M) elems
__global__ __launch_bounds__(256) void convert_kernel(
    const float* __restrict__ x, const float* __restrict__ Wq,
    const float* __restrict__ Wk, const float* __restrict__ Wv,
    const float* __restrict__ Wo, bf16_t* __restrict__ dst)
{
  const size_t idx = ((size_t)blockIdx.x * 256 + threadIdx.x) * 8;
  const size_t XN = (size_t)4096 * DMODEL;
  const float* src;
  size_t off;
  if (idx < XN) { src = x; off = idx; }
  else {
    size_t r = idx - XN;
    int q = (int)(r >> 20);
    off = r & ((size_t)(1u << 20) - 1);
    src = (q == 0) ? Wq : (q == 1) ? Wk : (q == 2) ? Wv : Wo;
  }
  f32x8 v = *(const f32x8*)(src + off);
  bf16x8 o;
  #pragma unroll
  for (int j = 0; j < 8; ++j) o[j] = (bf16_t)v[j];
  *(bf16x8*)(dst + idx) = o;
}

// ---------------- shared 128x128 GEMM core, BK=64 ----------------
// v10: K-step 32 -> 64. Two 32-K half-tiles staged per barrier pair ->
// barrier/vmcnt-drain count halved (the 2-phase structure's dominant
// overhead, m233). LDS 32KB (As+Bs), swizzled staging as before.
static __device__ __forceinline__ void gemm128(
    const bf16_t* __restrict__ A, const bf16_t* __restrict__ B,
    bf16_t* As, bf16_t* Bs, f32x4 (&acc)[4][4])
{
  const int t    = threadIdx.x;
  const int w    = t >> 6;
  const int lane = t & 63;
  const int col  = lane & 15;
  const int quad = lane >> 4;
  const int wm   = w >> 1;
  const int wn   = w & 1;

  const int sr = t >> 2;
  const int sc = (t & 3) ^ (sr & 3);          // swizzled source chunk
  const bf16_t* ga = A + (size_t)sr * DMODEL + sc * 8;
  const bf16_t* gb = B + (size_t)sr * DMODEL + sc * 8;
  bf16_t* la = As + w * 512;
  bf16_t* lb = Bs + w * 512;

  const int swz = (quad ^ (col & 3)) * 8;     // read-side XOR

  for (int kk = 0; kk < DMODEL; kk += 64) {
    // half 0 (cols kk..kk+31) at offset 0; half 1 (kk+32..kk+63) at 4096
    load_lds16(ga + kk,                            la);
    load_lds16(ga + (size_t)64 * DMODEL + kk,      la + 2048);
    load_lds16(ga + kk + 32,                       la + 4096);
    load_lds16(ga + (size_t)64 * DMODEL + kk + 32, la + 6144);
    load_lds16(gb + kk,                            lb);
    load_lds16(gb + (size_t)64 * DMODEL + kk,      lb + 2048);
    load_lds16(gb + kk + 32,                       lb + 4096);
    load_lds16(gb + (size_t)64 * DMODEL + kk + 32, lb + 6144);
    __syncthreads();

    #pragma unroll
    for (int hh = 0; hh < 2; ++hh) {
      bf16x8 af[4], bfr[4];
      #pragma unroll
      for (int i = 0; i < 4; ++i) {
        af[i]  = *(const bf16x8*)(As + hh * 4096 + (wm * 64 + i * 16 + col) * 32 + swz);
        bfr[i] = *(const bf16x8*)(Bs + hh * 4096 + (wn * 64 + i * 16 + col) * 32 + swz);
      }
      #pragma unroll
      for (int mt = 0; mt < 4; ++mt)
        #pragma unroll
        for (int nt = 0; nt < 4; ++nt)
          acc[mt][nt] = mfma_bf16(af[mt], bfr[nt], acc[mt][nt]);
    }
    __syncthreads();
  }
}

// ---------------- QKV projection ----------------
__global__ __launch_bounds__(256) void qkv_gemm_kernel(
    const bf16_t* __restrict__ xb, const bf16_t* __restrict__ Wall,
    bf16_t* __restrict__ Qb, bf16_t* __restrict__ Kb, bf16_t* __restrict__ Vt)
{
  __shared__ __align__(16) bf16_t As[128 * 64];
  __shared__ __align__(16) bf16_t Bs[128 * 64];
  f32x4 acc[4][4] = {};
  const int m0 = blockIdx.x * 128;
  const int n0 = blockIdx.y * 128;
  gemm128(xb + (size_t)m0 * DMODEL, Wall + (size_t)n0 * DMODEL, As, Bs, acc);

  const int t = threadIdx.x;
  const int lane = t & 63, w = t >> 6;
  const int col = lane & 15, quad = lane >> 4;
  const int wm = w >> 1, wn = w & 1;
  const int nw0 = n0 + wn * 64;
  const int wt  = nw0 >> 10;          // 0=Q, 1=K, 2=V
  const int h   = (nw0 >> 6) & 15;
  const int mbase = m0 + wm * 64;

  if (wt < 2) {
    bf16_t* Out = (wt == 0) ? Qb : Kb;
    #pragma unroll
    for (int mt = 0; mt < 4; ++mt) {
      #pragma unroll
      for (int nt = 0; nt < 4; ++nt) {
        const int d = nt * 16 + col;
        #pragma unroll
        for (int r = 0; r < 4; ++r) {
          const int m = mbase + mt * 16 + quad * 4 + r;
          const int b = m >> 11, s = m & (SEQ - 1);
          Out[((size_t)(b * NHEADS + h) * SEQ + s) * DH + d] = (bf16_t)acc[mt][nt][r];
        }
      }
    }
  } else {
    #pragma unroll
    for (int mt = 0; mt < 4; ++mt) {
      const int m = mbase + mt * 16 + quad * 4;
      const int b = m >> 11, s = m & (SEQ - 1);
      #pragma unroll
      for (int nt = 0; nt < 4; ++nt) {
        const int d = nt * 16 + col;
        bf16x4 v4 = { (bf16_t)acc[mt][nt][0], (bf16_t)acc[mt][nt][1],
                      (bf16_t)acc[mt][nt][2], (bf16_t)acc[mt][nt][3] };
        *(bf16x4*)(Vt + ((size_t)(b * NHEADS + h) * DH + d) * SEQ + s) = v4;
      }
    }
  }
}

// ---------------- RoPE (in-place on Q and K) ----------------
__global__ __launch_bounds__(256) void rope_kernel(
    bf16_t* __restrict__ Qb, bf16_t* __restrict__ Kb, const int* __restrict__ tpos)
{
  const int idx = blockIdx.x * 256 + threadIdx.x;
  const int i  = idx & 31;
  const int s  = (idx >> 5) & (SEQ - 1);
  const int bh = idx >> 16;

  const float pos  = (float)tpos[s];
  const float freq = expf((float)i * -0.28782313662425573f);
  const float ang  = pos * freq;
  const float cs = cosf(ang), sn = sinf(ang);

  const size_t base = ((size_t)bh * SEQ + s) * DH + 2 * i;
  {
    float e = (float)Qb[base], o = (float)Qb[base + 1];
    Qb[base]     = (bf16_t)(e * cs - o * sn);
    Qb[base + 1] = (bf16_t)(e * sn + o * cs);
  }
  {
    float e = (float)Kb[base], o = (float)Kb[base + 1];
    Kb[base]     = (bf16_t)(e * cs - o * sn);
    Kb[base + 1] = (bf16_t)(e * sn + o * cs);
  }
}

// ---------------- Flash attention v10 ----------------
// Exact v6 structure (known-best 49.2us: 4 waves x 16 q-rows, paired phases,
// grid (32,16)) + two local changes:
//  (a) s_setprio(1) around each MFMA pair (T5: +4-7% measured on attn, m191)
//  (b) kt-loop split by plane with the plane-0 P-fragment ds_read hoisted
//      between them: its lgkm latency hides under kt2/kt3 QK+exp instead of
//      sitting exposed right before PV.
__global__ __launch_bounds__(256) void attn_kernel(
    const bf16_t* __restrict__ Qb, const bf16_t* __restrict__ Kb,
    const bf16_t* __restrict__ Vt, bf16_t* __restrict__ attn)
{
  __shared__ __align__(16) bf16_t Ks[2][4096];   // 2 planes x 2048 elems
  __shared__ __align__(16) bf16_t Vs[2][4096];
  __shared__ __align__(16) bf16_t Ps[4][1280];   // per wave: 2 planes x 640

  const int t    = threadIdx.x;
  const int wave = t >> 6;
  const int lane = t & 63;
  const int col  = lane & 15;
  const int quad = lane >> 4;
  const int bh = blockIdx.x;
  const int h  = bh & 15;
  const int b  = bh >> 4;
  const int qtA = blockIdx.y;          // 0..15
  const int qtB = 31 - qtA;            // 16..31

  const size_t hoff = (size_t)(b * NHEADS + h) * SEQ * DH;
  const bf16_t* Qh = Qb + hoff;
  const bf16_t* Kh = Kb + hoff;
  const bf16_t* Vh = Vt + hoff;                // (d,s), row stride SEQ

  // Q B-fragments for both phases, pre-scaled by 1/8 * log2(e)
  const int qrA = qtA * 64 + wave * 16 + col;
  const int qrB = qtB * 64 + wave * 16 + col;
  bf16x8 qfA0 = *(const bf16x8*)(Qh + (size_t)qrA * DH + quad * 8);
  bf16x8 qfA1 = *(const bf16x8*)(Qh + (size_t)qrA * DH + 32 + quad * 8);
  bf16x8 qfB0 = *(const bf16x8*)(Qh + (size_t)qrB * DH + quad * 8);
  bf16x8 qfB1 = *(const bf16x8*)(Qh + (size_t)qrB * DH + 32 + quad * 8);
  #pragma unroll
  for (int j = 0; j < 8; ++j) {
    qfA0[j] = (bf16_t)((float)qfA0[j] * 0.1803368801111191f);
    qfA1[j] = (bf16_t)((float)qfA1[j] * 0.1803368801111191f);
    qfB0[j] = (bf16_t)((float)qfB0[j] * 0.1803368801111191f);
    qfB1[j] = (bf16_t)((float)qfB1[j] * 0.1803368801111191f);
  }

  // staging map: thread t -> row t>>2, 16B chunk t&3; dst = base + t*16B
  const int sr = t >> 2, sc = t & 3;
  const int lbase = t * 8;                     // elems
  const bf16_t* kg0 = Kh + (size_t)sr * DH + sc * 8;
  const bf16_t* vg0 = Vh + (size_t)sr * SEQ + sc * 8;

  // prologue: stage tile 0 into buf 0
  load_lds16(kg0,      &Ks[0][lbase]);
  load_lds16(kg0 + 32, &Ks[0][2048 + lbase]);
  load_lds16(vg0,      &Vs[0][lbase]);
  load_lds16(vg0 + 32, &Vs[0][2048 + lbase]);

  f32x4 o[4] = {};
  float lsum = 0.0f;
  bf16_t* P = Ps[wave];
  const int lim = wave * 16 + col;             // tile-local causal limit
  const int pwoff = col * 40 + (quad >> 1) * 8 + (quad & 1) * 4;

  bf16x8 q0 = qfA0, q1 = qfA1;
  int qcur = qtA;                              // current phase's q-tile
  int it = 0;                                  // k-tile index within phase

  for (int g = 0; g <= 32; ++g) {
    const int buf = g & 1;
    __syncthreads();   // tile for step g DMA complete; buf^1 free

    if (g < 32) {      // prefetch next k-tile (tile 0 of phase B at g==qtA)
      const int nk = (g == qtA) ? 0 : (it + 1);
      const bf16_t* kg = kg0 + (size_t)nk * 64 * DH;
      const bf16_t* vg = vg0 + nk * 64;
      bf16_t* Kd = Ks[buf ^ 1];
      bf16_t* Vd = Vs[buf ^ 1];
      load_lds16(kg,      Kd + lbase);
      load_lds16(kg + 32, Kd + 2048 + lbase);
      load_lds16(vg,      Vd + lbase);
      load_lds16(vg + 32, Vd + 2048 + lbase);
    }

    const bool diag = (it == qcur);
    const bf16_t* Kbuf = Ks[buf];

    // QK^T plane a (keys 0..31) + softmax -> P plane 0
    #pragma unroll
    for (int kt = 0; kt < 2; ++kt) {
      bf16x8 ka = *(const bf16x8*)(Kbuf + (16 * kt + col) * 32 + quad * 8);
      bf16x8 kb = *(const bf16x8*)(Kbuf + 2048 + (16 * kt + col) * 32 + quad * 8);
      f32x4 s = {};
      __builtin_amdgcn_s_setprio(1);
      s = mfma_bf16(ka, q0, s);
      s = mfma_bf16(kb, q1, s);
      __builtin_amdgcn_s_setprio(0);
      const int kl = kt * 16 + quad * 4;
      bf16x4 p4;
      #pragma unroll
      for (int r = 0; r < 4; ++r) {
        float p = (!diag || (kl + r <= lim)) ? __builtin_amdgcn_exp2f(s[r]) : 0.0f;
        lsum += p;
        p4[r] = (bf16_t)p;
      }
      *(bf16x4*)(P + (kt & 1) * 16 + pwoff) = p4;
    }

    // plane-0 P fragment read: latency hides under plane-b QK below
    bf16x8 pf0 = *(const bf16x8*)(P + col * 40 + quad * 8);

    // QK^T plane b (keys 32..63) + softmax -> P plane 1
    #pragma unroll
    for (int kt = 2; kt < 4; ++kt) {
      bf16x8 ka = *(const bf16x8*)(Kbuf + (16 * kt + col) * 32 + quad * 8);
      bf16x8 kb = *(const bf16x8*)(Kbuf + 2048 + (16 * kt + col) * 32 + quad * 8);
      f32x4 s = {};
      __builtin_amdgcn_s_setprio(1);
      s = mfma_bf16(ka, q0, s);
      s = mfma_bf16(kb, q1, s);
      __builtin_amdgcn_s_setprio(0);
      const int kl = kt * 16 + quad * 4;
      bf16x4 p4;
      #pragma unroll
      for (int r = 0; r < 4; ++r) {
        float p = (!diag || (kl + r <= lim)) ? __builtin_amdgcn_exp2f(s[r]) : 0.0f;
        lsum += p;
        p4[r] = (bf16_t)p;
      }
      *(bf16x4*)(P + 640 + (kt & 1) * 16 + pwoff) = p4;
    }

    bf16x8 pf1 = *(const bf16x8*)(P + 640 + col * 40 + quad * 8);

    // PV: o[d][q] += V' * P
    const bf16_t* Vbuf = Vs[buf];
    #pragma unroll
    for (int dt = 0; dt < 4; ++dt) {
      bf16x8 va = *(const bf16x8*)(Vbuf + (16 * dt + col) * 32 + quad * 8);
      bf16x8 vb = *(const bf16x8*)(Vbuf + 2048 + (16 * dt + col) * 32 + quad * 8);
      __builtin_amdgcn_s_setprio(1);
      o[dt] = mfma_bf16(va, pf0, o[dt]);
      o[dt] = mfma_bf16(vb, pf1, o[dt]);
      __builtin_amdgcn_s_setprio(0);
    }

    if (diag) {
      // finalize current phase: reduce lsum across quads, normalize, store
      float ls = lsum;
      ls += __shfl_xor(ls, 16, 64);
      ls += __shfl_xor(ls, 32, 64);
      const float inv = 1.0f / ls;
      const int q = qcur * 64 + wave * 16 + col;
      const size_t orow = (size_t)(b * SEQ + q) * DMODEL + h * DH;
      #pragma unroll
      for (int dt = 0; dt < 4; ++dt) {
        bf16x4 v4 = { (bf16_t)(o[dt][0] * inv), (bf16_t)(o[dt][1] * inv),
                      (bf16_t)(o[dt][2] * inv), (bf16_t)(o[dt][3] * inv) };
        *(bf16x4*)(attn + orow + dt * 16 + quad * 4) = v4;
      }
      // switch to phase B
      #pragma unroll
      for (int dt = 0; dt < 4; ++dt) o[dt] = f32x4{};
      lsum = 0.0f;
      q0 = qfB0; q1 = qfB1;
      qcur = qtB;
      it = 0;
    } else {
      ++it;
    }
  }
}

// ---------------- Output projection (-> f32 d_out) ----------------
__global__ __launch_bounds__(256) void out_gemm_kernel(
    const bf16_t* __restrict__ Ab, const bf16_t* __restrict__ Wob,
    float* __restrict__ out)
{
  __shared__ __align__(16) bf16_t As[128 * 64];
  __shared__ __align__(16) bf16_t Bs[128 * 64];
  f32x4 acc[4][4] = {};
  const int m0 = blockIdx.x * 128;
  const int n0 = blockIdx.y * 128;
  gemm128(Ab + (size_t)m0 * DMODEL, Wob + (size_t)n0 * DMODEL, As, Bs, acc);

  const int t = threadIdx.x;
  const int lane = t & 63, w = t >> 6;
  const int col = lane & 15, quad = lane >> 4;
  const int wm = w >> 1, wn = w & 1;
  const int mbase = m0 + wm * 64;
  const int nbase = n0 + wn * 64;

  #pragma unroll
  for (int mt = 0; mt < 4; ++mt)
    #pragma unroll
    for (int nt = 0; nt < 4; ++nt)
      #pragma unroll
      for (int r = 0; r < 4; ++r)
        out[(size_t)(mbase + mt * 16 + quad * 4 + r) * DMODEL + nbase + nt * 16 + col] =
            acc[mt][nt][r];
}

extern "C" void kernel_launch(void* const* d_in, const int* in_sizes, int n_in,
                              void* d_out, int out_size, void* d_ws, size_t ws_size,
                              hipStream_t stream)
{
  (void)in_sizes; (void)n_in; (void)out_size; (void)ws_size;
  const float* x  = (const float*)d_in[0];
  const float* Wq = (const float*)d_in[1];
  const float* Wk = (const float*)d_in[2];
  const float* Wv = (const float*)d_in[3];
  const float* Wo = (const float*)d_in[4];
  const int* tpos = (const int*)d_in[5];
  float* out = (float*)d_out;

  const size_t M1 = (size_t)1024 * 1024;
  bf16_t* xb    = (bf16_t*)d_ws;                  // 4M elems
  bf16_t* Wall  = xb + 4 * M1;                    // Wq|Wk|Wv (3M)
  bf16_t* Wob   = xb + 7 * M1;                    // 1M
  bf16_t* Qb    = xb + 8 * M1;                    // 4M  (b,h,s,d)
  bf16_t* Kb    = Qb + 4 * M1;                    // 4M  (b,h,s,d)
  bf16_t* Vt    = Kb + 4 * M1;                    // 4M  (b,h,d,s)
  bf16_t* attnb = Vt + 4 * M1;                    // 4M  (b*s, h*d)

  convert_kernel<<<dim3(4096, 1, 1), dim3(256, 1, 1), 0, stream>>>(
      x, Wq, Wk, Wv, Wo, xb);
  qkv_gemm_kernel<<<dim3(32, 24, 1), dim3(256, 1, 1), 0, stream>>>(
      xb, Wall, Qb, Kb, Vt);
  rope_kernel<<<dim3(8192, 1, 1), dim3(256, 1, 1), 0, stream>>>(Qb, Kb, tpos);
  attn_kernel<<<dim3(32, 16, 1), dim3(256, 1, 1), 0, stream>>>(
      Qb, Kb, Vt, attnb);
  out_gemm_kernel<<<dim3(32, 8, 1), dim3(256, 1, 1), 0, stream>>>(
      attnb, Wob, out);
}